// Round 5
// baseline (392.140 us; speedup 1.0000x reference)
//
#include <hip/hip_runtime.h>
#include <stdint.h>

#define NUM_HEADS 16
#define HIDDEN    2048
#define HEAD_SIZE 128
#define TOTAL     4096
#define SEQ       1024
#define QKV_N     (3*HIDDEN)   // 6144

typedef __bf16 bf16x8 __attribute__((ext_vector_type(8)));
typedef float  f32x4  __attribute__((ext_vector_type(4)));

__device__ __forceinline__ unsigned short f2bf(float f) {
  unsigned u = __float_as_uint(f);
  u += 0x7FFFu + ((u >> 16) & 1u);          // RNE
  return (unsigned short)(u >> 16);
}
__device__ __forceinline__ float bf2f(unsigned short h) {
  return __uint_as_float(((unsigned)h) << 16);
}
// async global->LDS, 16B per lane. LDS dest must be wave-uniform base + lane*16.
__device__ __forceinline__ void cp16(void* lds, const void* g) {
  __builtin_amdgcn_global_load_lds(
      (const __attribute__((address_space(1))) void*)g,
      (__attribute__((address_space(3))) void*)lds, 16, 0, 0);
}

// ---------------------------------------------------------------- fused convert (3 tensors)
__global__ __launch_bounds__(256) void f32_to_bf16_multi(
    const float* __restrict__ a, unsigned short* __restrict__ oa, int na,
    const float* __restrict__ b, unsigned short* __restrict__ ob, int nb,
    const float* __restrict__ c, unsigned short* __restrict__ oc, int nc)
{
  int i = (blockIdx.x * 256 + threadIdx.x) * 4;
  const float* src; unsigned short* dst;
  if (i < na)            { src = a; dst = oa; }
  else if (i < na + nb)  { i -= na; src = b; dst = ob; }
  else                   { i -= na + nb; if (i >= nc) return; src = c; dst = oc; }
  float4 v = *(const float4*)(src + i);
  unsigned p0 = (unsigned)f2bf(v.x) | ((unsigned)f2bf(v.y) << 16);
  unsigned p1 = (unsigned)f2bf(v.z) | ((unsigned)f2bf(v.w) << 16);
  uint2 pk; pk.x = p0; pk.y = p1;
  *(uint2*)(dst + i) = pk;
}

// ---------------------------------------------------------------- QKV GEMM (B^T input), 128x128
// C[i,j] = sum_k A[i,k]*B[j,k] + bias[j]
// Scatter bf16 -> Qb/Kb [B,H,S,D] WITH FUSED ROTARY on d<32 of Q,K; V -> Vt [B,H,D,S]
// Double-buffered LDS, one barrier per 32-K step. 16B-chunk XOR swizzle: conflict-free.
__global__ __launch_bounds__(256) void gemm_qkv(
    const unsigned short* __restrict__ A,   // [M][K] bf16
    const unsigned short* __restrict__ B,   // [N][K] bf16
    const float* __restrict__ bias,         // [N]
    const int* __restrict__ pos_ids,        // [TOTAL]
    unsigned short* __restrict__ Qb,
    unsigned short* __restrict__ Kb,
    unsigned short* __restrict__ Vt,
    int M, int N, int K)
{
  __shared__ unsigned short lsA[2][128*32]; // 2 x 8 KB, row pitch 64B
  __shared__ unsigned short lsB[2][128*32];
  const int tid  = threadIdx.x;
  const int w    = tid >> 6, lane = tid & 63;
  const int quad = lane >> 4, lm = lane & 15;
  const int wm   = w & 1, wn = w >> 1;
  const int mBase = blockIdx.y * 128;
  const int nBase = blockIdx.x * 128;
  const int swz = (lm >> 1) & 3;            // read-side chunk swizzle (row>>1)&3

  const f32x4 zero4 = {0.f, 0.f, 0.f, 0.f};
  f32x4 acc[4][4];
#pragma unroll
  for (int i = 0; i < 4; i++)
#pragma unroll
    for (int j = 0; j < 4; j++) acc[i][j] = zero4;

  const int cg = ((tid & 3) ^ ((tid >> 3) & 3)) * 16;  // swizzled global 16B chunk

  auto stage = [&](int bufi, int k0) {
#pragma unroll
    for (int i = 0; i < 2; i++) {
      int off = i * 4096 + tid * 16;
      int row = off >> 6;
      cp16((char*)&lsA[bufi][0] + off, (const char*)(A + (size_t)(mBase + row) * K + k0) + cg);
    }
#pragma unroll
    for (int i = 0; i < 2; i++) {
      int off = i * 4096 + tid * 16;
      int row = off >> 6;
      cp16((char*)&lsB[bufi][0] + off, (const char*)(B + (size_t)(nBase + row) * K + k0) + cg);
    }
  };

  int buf = 0;
  stage(0, 0);

  for (int k0 = 0; k0 < K; k0 += 32) {
    __syncthreads();                         // drains prefetch of `buf` + prev reads
    bf16x8 af[4], bfr[4];
#pragma unroll
    for (int mf = 0; mf < 4; mf++)
      af[mf] = *(const bf16x8*)(&lsA[buf][(wm * 64 + mf * 16 + lm) * 32 + (quad ^ swz) * 8]);
#pragma unroll
    for (int nf = 0; nf < 4; nf++)
      bfr[nf] = *(const bf16x8*)(&lsB[buf][(wn * 64 + nf * 16 + lm) * 32 + (quad ^ swz) * 8]);
    if (k0 + 32 < K) stage(buf ^ 1, k0 + 32);   // prefetch; lands by NEXT barrier
#pragma unroll
    for (int mf = 0; mf < 4; mf++)
#pragma unroll
      for (int nf = 0; nf < 4; nf++)
        acc[mf][nf] = __builtin_amdgcn_mfma_f32_16x16x32_bf16(af[mf], bfr[nf], acc[mf][nf], 0, 0, 0);
    buf ^= 1;
  }

  // epilogue: C layout col=lane&15, row=quad*4+r (m89-verified)
  const int col0 = nBase + wn * 64;          // wave-uniform 64-col window
  const int chunk = col0 >> 7;               // (head, q/k/v)
  const int hh = chunk / 3, t = chunk - 3 * hh;
  const bool lower = ((col0 >> 6) & 1) == 0; // d in [0,64) vs [64,128)
  if (t == 2) {                              // V: write transposed [B,H,D,S], 4 s packed / store
#pragma unroll
    for (int nf = 0; nf < 4; nf++) {
      int col = col0 + nf * 16 + lm;
      float bv = bias[col];
      int d = col & 127;
#pragma unroll
      for (int mf = 0; mf < 4; mf++) {
        int row0 = mBase + wm * 64 + mf * 16 + quad * 4;
        int b = row0 >> 10, s0 = row0 & 1023;
        unsigned u0 = (unsigned)f2bf(acc[mf][nf][0] + bv) | ((unsigned)f2bf(acc[mf][nf][1] + bv) << 16);
        unsigned u1 = (unsigned)f2bf(acc[mf][nf][2] + bv) | ((unsigned)f2bf(acc[mf][nf][3] + bv) << 16);
        uint2 pk; pk.x = u0; pk.y = u1;
        *(uint2*)(Vt + ((size_t)(b * NUM_HEADS + hh) * HEAD_SIZE + d) * SEQ + s0) = pk;
      }
    }
  } else {
    unsigned short* dst = (t == 0) ? Qb : Kb;
    if (lower) {
      // nf=0 (d=lm) pairs with nf=1 (d=lm+16): fused NeoX rotary. nf=2,3 pass-through.
      const float inv = exp2f(-0.8304820237f * (float)lm);   // 10000^(-lm/16)
      const float bv0 = bias[col0 + lm];
      const float bv1 = bias[col0 + 16 + lm];
#pragma unroll
      for (int mf = 0; mf < 4; mf++) {
        int row0 = mBase + wm * 64 + mf * 16 + quad * 4;
#pragma unroll
        for (int r = 0; r < 4; r++) {
          int row = row0 + r;
          int b = row >> 10, s = row & 1023;
          float pos = (float)pos_ids[row];
          float sn, cs;
          sincosf(pos * inv, &sn, &cs);
          float x1 = acc[mf][0][r] + bv0;
          float x2 = acc[mf][1][r] + bv1;
          size_t rb = ((size_t)(b * NUM_HEADS + hh) * SEQ + s) * HEAD_SIZE;
          dst[rb + lm]      = f2bf(x1 * cs - x2 * sn);
          dst[rb + 16 + lm] = f2bf(x1 * sn + x2 * cs);
        }
      }
#pragma unroll
      for (int nf = 2; nf < 4; nf++) {
        float bv = bias[col0 + nf * 16 + lm];
        int d = nf * 16 + lm;
#pragma unroll
        for (int mf = 0; mf < 4; mf++) {
          int row0 = mBase + wm * 64 + mf * 16 + quad * 4;
#pragma unroll
          for (int r = 0; r < 4; r++) {
            int row = row0 + r;
            int b = row >> 10, s = row & 1023;
            dst[((size_t)(b * NUM_HEADS + hh) * SEQ + s) * HEAD_SIZE + d] = f2bf(acc[mf][nf][r] + bv);
          }
        }
      }
    } else {
#pragma unroll
      for (int nf = 0; nf < 4; nf++) {
        float bv = bias[col0 + nf * 16 + lm];
        int d = 64 + nf * 16 + lm;
#pragma unroll
        for (int mf = 0; mf < 4; mf++) {
          int row0 = mBase + wm * 64 + mf * 16 + quad * 4;
#pragma unroll
          for (int r = 0; r < 4; r++) {
            int row = row0 + r;
            int b = row >> 10, s = row & 1023;
            dst[((size_t)(b * NUM_HEADS + hh) * SEQ + s) * HEAD_SIZE + d] = f2bf(acc[mf][nf][r] + bv);
          }
        }
      }
    }
  }
}

// ---------------------------------------------------------------- dense GEMM, 64x128 tiles
// grid (N/128, M/64) = (16, 64) = 1024 blocks = 4 blocks/CU (vs 2 at 128x128 -> latency-bound).
// Wave w owns 32 rows x 64 cols: acc[2][4], 8 MFMA / K-step. Same dbuf + swizzle as gemm_qkv.
__global__ __launch_bounds__(256) void gemm_dense64(
    const unsigned short* __restrict__ A,   // [M][K] bf16
    const unsigned short* __restrict__ B,   // [N][K] bf16
    const float* __restrict__ bias,         // [N]
    float* __restrict__ Cf,                 // [M][N] fp32
    int M, int N, int K)
{
  __shared__ unsigned short lsA[2][64*32];  // 2 x 4 KB
  __shared__ unsigned short lsB[2][128*32]; // 2 x 8 KB
  const int tid  = threadIdx.x;
  const int w    = tid >> 6, lane = tid & 63;
  const int quad = lane >> 4, lm = lane & 15;
  const int wm   = w & 1, wn = w >> 1;
  const int mBase = blockIdx.y * 64;
  const int nBase = blockIdx.x * 128;
  const int swz = (lm >> 1) & 3;

  const f32x4 zero4 = {0.f, 0.f, 0.f, 0.f};
  f32x4 acc[2][4];
#pragma unroll
  for (int i = 0; i < 2; i++)
#pragma unroll
    for (int j = 0; j < 4; j++) acc[i][j] = zero4;

  const int cg = ((tid & 3) ^ ((tid >> 3) & 3)) * 16;

  auto stage = [&](int bufi, int k0) {
    {
      int off = tid * 16;                    // A: 64 rows x 64B = 4KB, one pass
      int row = off >> 6;
      cp16((char*)&lsA[bufi][0] + off, (const char*)(A + (size_t)(mBase + row) * K + k0) + cg);
    }
#pragma unroll
    for (int i = 0; i < 2; i++) {            // B: 128 rows x 64B = 8KB
      int off = i * 4096 + tid * 16;
      int row = off >> 6;
      cp16((char*)&lsB[bufi][0] + off, (const char*)(B + (size_t)(nBase + row) * K + k0) + cg);
    }
  };

  int buf = 0;
  stage(0, 0);

  for (int k0 = 0; k0 < K; k0 += 32) {
    __syncthreads();
    bf16x8 af[2], bfr[4];
#pragma unroll
    for (int mf = 0; mf < 2; mf++)
      af[mf] = *(const bf16x8*)(&lsA[buf][(wm * 32 + mf * 16 + lm) * 32 + (quad ^ swz) * 8]);
#pragma unroll
    for (int nf = 0; nf < 4; nf++)
      bfr[nf] = *(const bf16x8*)(&lsB[buf][(wn * 64 + nf * 16 + lm) * 32 + (quad ^ swz) * 8]);
    if (k0 + 32 < K) stage(buf ^ 1, k0 + 32);
#pragma unroll
    for (int mf = 0; mf < 2; mf++)
#pragma unroll
      for (int nf = 0; nf < 4; nf++)
        acc[mf][nf] = __builtin_amdgcn_mfma_f32_16x16x32_bf16(af[mf], bfr[nf], acc[mf][nf], 0, 0, 0);
    buf ^= 1;
  }

#pragma unroll
  for (int nf = 0; nf < 4; nf++) {
    int col = nBase + wn * 64 + nf * 16 + lm;
    float bv = bias[col];
#pragma unroll
    for (int mf = 0; mf < 2; mf++) {
      int row0 = mBase + wm * 32 + mf * 16 + quad * 4;
#pragma unroll
      for (int r = 0; r < 4; r++)
        Cf[(size_t)(row0 + r) * N + col] = acc[mf][nf][r] + bv;
    }
  }
}

// ---------------------------------------------------------------- flash attention (UNCHANGED r3)
// grid (64 bh, 8 pair). Each block handles Q-tiles qa=15-pair and qb=pair (64 rows each)
// -> exactly 17 k-tile iterations per block (uniform load). Double-buffered K/V staging
// with prefetch issued AFTER the barrier. 4 waves; wave w owns q-rows w*16..w*16+15.
__global__ __launch_bounds__(256, 2) void flash_attn_k(
    const unsigned short* __restrict__ Q,
    const unsigned short* __restrict__ K,
    const unsigned short* __restrict__ VT,   // [B,H,D,S]
    unsigned short* __restrict__ O)          // [TOTAL][HIDDEN] bf16
{
  const int bh = blockIdx.x;
  const int pair = blockIdx.y;
  const int qa = 15 - pair, qb = pair;
  const int b = bh >> 4, h = bh & 15;
  const size_t base = (size_t)bh * SEQ * HEAD_SIZE;
  const unsigned short* Qp = Q + base;
  const unsigned short* Kp = K + base;
  const unsigned short* Vp = VT + base;      // [d][s]

  __shared__ unsigned short Ks[2][4][64*32]; // 2 x 16 KB
  __shared__ unsigned short Vl[2][128*64];   // 2 x 16 KB
  __shared__ unsigned short Ps[64][72];      // 9 KB (pitch 144B, 16B-aligned rows)

  const int tid  = threadIdx.x;
  const int w    = tid >> 6, lane = tid & 63;
  const int quad = lane >> 4, lm = lane & 15;
  const int swz4 = (lm >> 1) & 3;            // Ks read swizzle
  const int swz8 = lm & 7;                   // Vl read swizzle (d&7)
  const int cgK = ((tid & 3) ^ ((tid >> 3) & 3)) * 8;   // halves
  const int cgV = ((tid & 7) ^ ((tid >> 3) & 7)) * 8;   // halves

  const float K1 = 0.1275156876f;            // (1/sqrt(128)) * log2(e)
  const f32x4 zero4 = {0.f, 0.f, 0.f, 0.f};
  const __bf16 one = (__bf16)1.0f;
  const bf16x8 vones = {one, one, one, one, one, one, one, one};

  auto stage = [&](int buf, int kt) {
    const unsigned short* krow = Kp + (size_t)(kt * 64 + (tid >> 2)) * HEAD_SIZE + cgK;
#pragma unroll
    for (int kk = 0; kk < 4; kk++)
      cp16((char*)&Ks[buf][kk][0] + tid * 16, krow + kk * 32);
#pragma unroll
    for (int i = 0; i < 4; i++) {
      int off = i * 4096 + tid * 16;
      int d = off >> 7;
      cp16((char*)&Vl[buf][0] + off, Vp + (size_t)d * SEQ + kt * 64 + cgV);
    }
  };

  int buf = 0;
  stage(0, 0);

  for (int ph = 0; ph < 2; ph++) {
    const int qt = ph ? qb : qa;
    bf16x8 qf[4];
    {
      const unsigned short* qrow = Qp + (size_t)(qt * 64 + w * 16 + lm) * HEAD_SIZE;
#pragma unroll
      for (int kk = 0; kk < 4; kk++)
        qf[kk] = *(const bf16x8*)(qrow + kk * 32 + quad * 8);
    }
    float m_r[4];
#pragma unroll
    for (int r = 0; r < 4; r++) m_r[r] = -1e30f;
    f32x4 lacc = zero4;
    f32x4 o[8];
#pragma unroll
    for (int i = 0; i < 8; i++) o[i] = zero4;

    for (int kt = 0; kt <= qt; ++kt) {
      __syncthreads();                       // staging of `buf` landed; buf^1 free
      bool last = (ph == 1) && (kt == qt);
      if (!last) stage(buf ^ 1, (kt < qt) ? kt + 1 : 0);   // prefetch (drained at NEXT barrier)

      // S = Q K^T
      f32x4 sf[4];
#pragma unroll
      for (int nf = 0; nf < 4; nf++) {
        f32x4 accs = zero4;
#pragma unroll
        for (int kk = 0; kk < 4; kk++) {
          bf16x8 kfrag = *(const bf16x8*)(&Ks[buf][kk][(nf * 16 + lm) * 32 + (quad ^ swz4) * 8]);
          accs = __builtin_amdgcn_mfma_f32_16x16x32_bf16(qf[kk], kfrag, accs, 0, 0, 0);
        }
        sf[nf] = accs;
      }
      if (kt == qt) {                        // diagonal tile: causal mask
        int qrow0 = qt * 64 + w * 16 + quad * 4;
#pragma unroll
        for (int nf = 0; nf < 4; nf++) {
          int col = kt * 64 + nf * 16 + lm;
#pragma unroll
          for (int r = 0; r < 4; r++)
            if (col > qrow0 + r) sf[nf][r] = -1e30f;
        }
      }
      // online softmax: row max across 16 lanes, alpha rescale
      float alpha[4];
#pragma unroll
      for (int r = 0; r < 4; r++) {
        float v = fmaxf(fmaxf(sf[0][r], sf[1][r]), fmaxf(sf[2][r], sf[3][r]));
        v = fmaxf(v, __shfl_xor(v, 1));
        v = fmaxf(v, __shfl_xor(v, 2));
        v = fmaxf(v, __shfl_xor(v, 4));
        v = fmaxf(v, __shfl_xor(v, 8));
        float mn = fmaxf(m_r[r], v);
        alpha[r] = exp2f((m_r[r] - mn) * K1);
        m_r[r] = mn;
      }
#pragma unroll
      for (int nf = 0; nf < 4; nf++)
#pragma unroll
        for (int r = 0; r < 4; r++) {
          float p = exp2f((sf[nf][r] - m_r[r]) * K1);
          Ps[w * 16 + quad * 4 + r][nf * 16 + lm] = f2bf(p);
        }
#pragma unroll
      for (int df = 0; df < 8; df++)
#pragma unroll
        for (int r = 0; r < 4; r++) o[df][r] *= alpha[r];
#pragma unroll
      for (int r = 0; r < 4; r++) lacc[r] *= alpha[r];

      // O += P V ; l += P * 1   (P rows wave-private: lgkmcnt-only hazard)
#pragma unroll
      for (int ks = 0; ks < 2; ks++) {
        bf16x8 pf = *(const bf16x8*)(&Ps[w * 16 + lm][ks * 32 + quad * 8]);
        lacc = __builtin_amdgcn_mfma_f32_16x16x32_bf16(pf, vones, lacc, 0, 0, 0);
#pragma unroll
        for (int df = 0; df < 8; df++) {
          bf16x8 vf = *(const bf16x8*)(&Vl[buf][(df * 16 + lm) * 64 + (((ks * 4 + quad) ^ swz8)) * 8]);
          o[df] = __builtin_amdgcn_mfma_f32_16x16x32_bf16(pf, vf, o[df], 0, 0, 0);
        }
      }
      buf ^= 1;
    }

    // finalize this Q-tile
    float rl[4];
#pragma unroll
    for (int r = 0; r < 4; r++) rl[r] = 1.f / lacc[r];
    int row0 = b * SEQ + qt * 64 + w * 16 + quad * 4;
#pragma unroll
    for (int df = 0; df < 8; df++) {
      int col = h * HEAD_SIZE + df * 16 + lm;
#pragma unroll
      for (int r = 0; r < 4; r++)
        O[(size_t)(row0 + r) * HIDDEN + col] = f2bf(o[df][r] * rl[r]);
    }
  }
}

// ---------------------------------------------------------------- launch
extern "C" void kernel_launch(void* const* d_in, const int* in_sizes, int n_in,
                              void* d_out, int out_size, void* d_ws, size_t ws_size,
                              hipStream_t stream)
{
  const float* hs   = (const float*)d_in[0];
  const float* wqkv = (const float*)d_in[2];
  const float* bqkv = (const float*)d_in[3];
  const float* wd   = (const float*)d_in[4];
  const float* bd   = (const float*)d_in[5];
  const int*   pos  = (const int*)d_in[6];

  char* ws = (char*)d_ws;
  unsigned short* hsb = (unsigned short*)ws;  ws += (size_t)TOTAL * HIDDEN * 2;   // 16.8 MB
  unsigned short* wqb = (unsigned short*)ws;  ws += (size_t)QKV_N * HIDDEN * 2;   // 25.2 MB
  unsigned short* wdb = (unsigned short*)ws;  ws += (size_t)HIDDEN * HIDDEN * 2;  //  8.4 MB
  unsigned short* Qb  = (unsigned short*)ws;  ws += (size_t)TOTAL * HIDDEN * 2;
  unsigned short* Kb  = (unsigned short*)ws;  ws += (size_t)TOTAL * HIDDEN * 2;
  unsigned short* Vt  = (unsigned short*)ws;  ws += (size_t)TOTAL * HIDDEN * 2;   // [B,H,D,S]
  unsigned short* attnb = hsb;               // hsb dead after QKV GEMM
  if (ws_size < (size_t)(ws - (char*)d_ws)) return;  // ~100.8 MB needed

  const int na = TOTAL * HIDDEN, nb = QKV_N * HIDDEN, nc = HIDDEN * HIDDEN;
  f32_to_bf16_multi<<<(na + nb + nc) / 1024, 256, 0, stream>>>(
      hs, hsb, na, wqkv, wqb, nb, wd, wdb, nc);

  gemm_qkv<<<dim3(QKV_N / 128, TOTAL / 128), 256, 0, stream>>>(
      hsb, wqb, bqkv, pos, Qb, Kb, Vt, TOTAL, QKV_N, HIDDEN);

  flash_attn_k<<<dim3(64, 8), 256, 0, stream>>>(Qb, Kb, Vt, attnb);

  gemm_dense64<<<dim3(HIDDEN / 128, TOTAL / 64), 256, 0, stream>>>(
      attnb, wdb, bd, (float*)d_out, TOTAL, HIDDEN, HIDDEN);
}

// Round 6
// 377.913 us; speedup vs baseline: 1.0376x; 1.0376x over previous
//
#include <hip/hip_runtime.h>
#include <stdint.h>

#define NUM_HEADS 16
#define HIDDEN    2048
#define HEAD_SIZE 128
#define TOTAL     4096
#define SEQ       1024
#define QKV_N     (3*HIDDEN)   // 6144

typedef __bf16 bf16x8 __attribute__((ext_vector_type(8)));
typedef float  f32x4  __attribute__((ext_vector_type(4)));

__device__ __forceinline__ unsigned short f2bf(float f) {
  unsigned u = __float_as_uint(f);
  u += 0x7FFFu + ((u >> 16) & 1u);          // RNE
  return (unsigned short)(u >> 16);
}
__device__ __forceinline__ float bf2f(unsigned short h) {
  return __uint_as_float(((unsigned)h) << 16);
}
// async global->LDS, 16B per lane. LDS dest must be wave-uniform base + lane*16.
__device__ __forceinline__ void cp16(void* lds, const void* g) {
  __builtin_amdgcn_global_load_lds(
      (const __attribute__((address_space(1))) void*)g,
      (__attribute__((address_space(3))) void*)lds, 16, 0, 0);
}

// ---------------------------------------------------------------- fused convert (3 tensors)
__global__ __launch_bounds__(256) void f32_to_bf16_multi(
    const float* __restrict__ a, unsigned short* __restrict__ oa, int na,
    const float* __restrict__ b, unsigned short* __restrict__ ob, int nb,
    const float* __restrict__ c, unsigned short* __restrict__ oc, int nc)
{
  int i = (blockIdx.x * 256 + threadIdx.x) * 4;
  const float* src; unsigned short* dst;
  if (i < na)            { src = a; dst = oa; }
  else if (i < na + nb)  { i -= na; src = b; dst = ob; }
  else                   { i -= na + nb; if (i >= nc) return; src = c; dst = oc; }
  float4 v = *(const float4*)(src + i);
  unsigned p0 = (unsigned)f2bf(v.x) | ((unsigned)f2bf(v.y) << 16);
  unsigned p1 = (unsigned)f2bf(v.z) | ((unsigned)f2bf(v.w) << 16);
  uint2 pk; pk.x = p0; pk.y = p1;
  *(uint2*)(dst + i) = pk;
}

// ---------------------------------------------------------------- QKV GEMM, FAT WAVES
// Block = 128 rows x 256 cols, 4 waves, wave-tile 64x128 (acc 4 mf x 8 nf f32x4 = 128 AGPR).
// LDS reads per wave-iter: A 4KB + B 8KB for 64 MFMA-FLOP-equiv -> 36KB/blk-iter vs 48KB
// at 64x64 wave-tiles (the LDS pipe is the most-loaded pipe at ~47%; this cuts its traffic).
// Each wave's 128-col window = exactly one (head, q/k/v) chunk -> uniform epilogue.
// Double-buffered staging, reads->prefetch->MFMA order (r4 pipeline). XOR swizzle: 2-way max.
__global__ __launch_bounds__(256, 2) void gemm_qkv(
    const unsigned short* __restrict__ A,   // [M][K] bf16
    const unsigned short* __restrict__ B,   // [N][K] bf16
    const float* __restrict__ bias,         // [N]
    const int* __restrict__ pos_ids,        // [TOTAL]
    unsigned short* __restrict__ Qb,
    unsigned short* __restrict__ Kb,
    unsigned short* __restrict__ Vt,
    int M, int N, int K)
{
  __shared__ unsigned short lsA[2][128*32]; // 2 x 8 KB, row pitch 64B
  __shared__ unsigned short lsB[2][256*32]; // 2 x 16 KB
  const int tid  = threadIdx.x;
  const int w    = tid >> 6, lane = tid & 63;
  const int quad = lane >> 4, lm = lane & 15;
  const int wm   = w >> 1, wn = w & 1;      // row-half (64), col-half (128)
  const int mBase = blockIdx.y * 128;
  const int nBase = blockIdx.x * 256;
  const int swz = (lm >> 1) & 3;            // read-side chunk swizzle (row>>1)&3

  const f32x4 zero4 = {0.f, 0.f, 0.f, 0.f};
  f32x4 acc[4][8];
#pragma unroll
  for (int i = 0; i < 4; i++)
#pragma unroll
    for (int j = 0; j < 8; j++) acc[i][j] = zero4;

  const int cg = ((tid & 3) ^ ((tid >> 3) & 3)) * 16;  // swizzled global 16B chunk

  auto stage = [&](int bufi, int k0) {
#pragma unroll
    for (int i = 0; i < 2; i++) {           // A: 128 rows x 64B
      int off = i * 4096 + tid * 16;
      int row = off >> 6;
      cp16((char*)&lsA[bufi][0] + off, (const char*)(A + (size_t)(mBase + row) * K + k0) + cg);
    }
#pragma unroll
    for (int i = 0; i < 4; i++) {           // B: 256 rows x 64B
      int off = i * 4096 + tid * 16;
      int row = off >> 6;
      cp16((char*)&lsB[bufi][0] + off, (const char*)(B + (size_t)(nBase + row) * K + k0) + cg);
    }
  };

  int buf = 0;
  stage(0, 0);

  for (int k0 = 0; k0 < K; k0 += 32) {
    __syncthreads();                         // prefetch of `buf` landed
    bf16x8 af[4], bfr[8];
#pragma unroll
    for (int mf = 0; mf < 4; mf++)
      af[mf] = *(const bf16x8*)(&lsA[buf][(wm * 64 + mf * 16 + lm) * 32 + (quad ^ swz) * 8]);
#pragma unroll
    for (int nf = 0; nf < 8; nf++)
      bfr[nf] = *(const bf16x8*)(&lsB[buf][(wn * 128 + nf * 16 + lm) * 32 + (quad ^ swz) * 8]);
    if (k0 + 32 < K) stage(buf ^ 1, k0 + 32);   // prefetch; lands by NEXT barrier
#pragma unroll
    for (int mf = 0; mf < 4; mf++)
#pragma unroll
      for (int nf = 0; nf < 8; nf++)
        acc[mf][nf] = __builtin_amdgcn_mfma_f32_16x16x32_bf16(af[mf], bfr[nf], acc[mf][nf], 0, 0, 0);
    buf ^= 1;
  }

  // epilogue: C layout col=lane&15, row=quad*4+r. Wave's 128 cols = one (head, q/k/v) chunk.
  const int col0 = nBase + wn * 128;         // wave-uniform, multiple of 128
  const int chunk = col0 >> 7;
  const int hh = chunk / 3, t = chunk - 3 * hh;
  if (t == 2) {                              // V: write transposed [B,H,D,S], 4 s packed / store
#pragma unroll
    for (int nf = 0; nf < 8; nf++) {
      int d = nf * 16 + lm;
      float bv = bias[col0 + d];
#pragma unroll
      for (int mf = 0; mf < 4; mf++) {
        int row0 = mBase + wm * 64 + mf * 16 + quad * 4;
        int b = row0 >> 10, s0 = row0 & 1023;
        unsigned u0 = (unsigned)f2bf(acc[mf][nf][0] + bv) | ((unsigned)f2bf(acc[mf][nf][1] + bv) << 16);
        unsigned u1 = (unsigned)f2bf(acc[mf][nf][2] + bv) | ((unsigned)f2bf(acc[mf][nf][3] + bv) << 16);
        uint2 pk; pk.x = u0; pk.y = u1;
        *(uint2*)(Vt + ((size_t)(b * NUM_HEADS + hh) * HEAD_SIZE + d) * SEQ + s0) = pk;
      }
    }
  } else {
    unsigned short* dst = (t == 0) ? Qb : Kb;
    // nf=0 (d=lm) pairs with nf=1 (d=lm+16): fused NeoX rotary.
    {
      const float inv = exp2f(-0.8304820237f * (float)lm);   // 10000^(-lm/16)
      const float bv0 = bias[col0 + lm];
      const float bv1 = bias[col0 + 16 + lm];
#pragma unroll
      for (int mf = 0; mf < 4; mf++) {
        int row0 = mBase + wm * 64 + mf * 16 + quad * 4;
#pragma unroll
        for (int r = 0; r < 4; r++) {
          int row = row0 + r;
          int b = row >> 10, s = row & 1023;
          float pos = (float)pos_ids[row];
          float sn, cs;
          sincosf(pos * inv, &sn, &cs);
          float x1 = acc[mf][0][r] + bv0;
          float x2 = acc[mf][1][r] + bv1;
          size_t rb = ((size_t)(b * NUM_HEADS + hh) * SEQ + s) * HEAD_SIZE;
          dst[rb + lm]      = f2bf(x1 * cs - x2 * sn);
          dst[rb + 16 + lm] = f2bf(x1 * sn + x2 * cs);
        }
      }
    }
#pragma unroll
    for (int nf = 2; nf < 8; nf++) {
      int d = nf * 16 + lm;
      float bv = bias[col0 + d];
#pragma unroll
      for (int mf = 0; mf < 4; mf++) {
        int row0 = mBase + wm * 64 + mf * 16 + quad * 4;
#pragma unroll
        for (int r = 0; r < 4; r++) {
          int row = row0 + r;
          int b = row >> 10, s = row & 1023;
          dst[((size_t)(b * NUM_HEADS + hh) * SEQ + s) * HEAD_SIZE + d] = f2bf(acc[mf][nf][r] + bv);
        }
      }
    }
  }
}

// ---------------------------------------------------------------- dense GEMM (r4 version: 128x128 dbuf)
__global__ __launch_bounds__(256) void gemm_dense(
    const unsigned short* __restrict__ A,   // [M][K] bf16
    const unsigned short* __restrict__ B,   // [N][K] bf16
    const float* __restrict__ bias,         // [N]
    float* __restrict__ Cf,                 // [M][N] fp32
    int M, int N, int K)
{
  __shared__ unsigned short lsA[2][128*32];
  __shared__ unsigned short lsB[2][128*32];
  const int tid  = threadIdx.x;
  const int w    = tid >> 6, lane = tid & 63;
  const int quad = lane >> 4, lm = lane & 15;
  const int wm   = w & 1, wn = w >> 1;
  const int mBase = blockIdx.y * 128;
  const int nBase = blockIdx.x * 128;
  const int swz = (lm >> 1) & 3;

  const f32x4 zero4 = {0.f, 0.f, 0.f, 0.f};
  f32x4 acc[4][4];
#pragma unroll
  for (int i = 0; i < 4; i++)
#pragma unroll
    for (int j = 0; j < 4; j++) acc[i][j] = zero4;

  const int cg = ((tid & 3) ^ ((tid >> 3) & 3)) * 16;

  auto stage = [&](int bufi, int k0) {
#pragma unroll
    for (int i = 0; i < 2; i++) {
      int off = i * 4096 + tid * 16;
      int row = off >> 6;
      cp16((char*)&lsA[bufi][0] + off, (const char*)(A + (size_t)(mBase + row) * K + k0) + cg);
    }
#pragma unroll
    for (int i = 0; i < 2; i++) {
      int off = i * 4096 + tid * 16;
      int row = off >> 6;
      cp16((char*)&lsB[bufi][0] + off, (const char*)(B + (size_t)(nBase + row) * K + k0) + cg);
    }
  };

  int buf = 0;
  stage(0, 0);

  for (int k0 = 0; k0 < K; k0 += 32) {
    __syncthreads();
    bf16x8 af[4], bfr[4];
#pragma unroll
    for (int mf = 0; mf < 4; mf++)
      af[mf] = *(const bf16x8*)(&lsA[buf][(wm * 64 + mf * 16 + lm) * 32 + (quad ^ swz) * 8]);
#pragma unroll
    for (int nf = 0; nf < 4; nf++)
      bfr[nf] = *(const bf16x8*)(&lsB[buf][(wn * 64 + nf * 16 + lm) * 32 + (quad ^ swz) * 8]);
    if (k0 + 32 < K) stage(buf ^ 1, k0 + 32);
#pragma unroll
    for (int mf = 0; mf < 4; mf++)
#pragma unroll
      for (int nf = 0; nf < 4; nf++)
        acc[mf][nf] = __builtin_amdgcn_mfma_f32_16x16x32_bf16(af[mf], bfr[nf], acc[mf][nf], 0, 0, 0);
    buf ^= 1;
  }

#pragma unroll
  for (int nf = 0; nf < 4; nf++) {
    int col = nBase + wn * 64 + nf * 16 + lm;
    float bv = bias[col];
#pragma unroll
    for (int mf = 0; mf < 4; mf++) {
      int row0 = mBase + wm * 64 + mf * 16 + quad * 4;
#pragma unroll
      for (int r = 0; r < 4; r++)
        Cf[(size_t)(row0 + r) * N + col] = acc[mf][nf][r] + bv;
    }
  }
}

// ---------------------------------------------------------------- flash attention (UNCHANGED r3)
// grid (64 bh, 8 pair). Q-tiles qa=15-pair & qb=pair -> 17 k-iters/block uniform.
__global__ __launch_bounds__(256, 2) void flash_attn_k(
    const unsigned short* __restrict__ Q,
    const unsigned short* __restrict__ K,
    const unsigned short* __restrict__ VT,   // [B,H,D,S]
    unsigned short* __restrict__ O)          // [TOTAL][HIDDEN] bf16
{
  const int bh = blockIdx.x;
  const int pair = blockIdx.y;
  const int qa = 15 - pair, qb = pair;
  const int b = bh >> 4, h = bh & 15;
  const size_t base = (size_t)bh * SEQ * HEAD_SIZE;
  const unsigned short* Qp = Q + base;
  const unsigned short* Kp = K + base;
  const unsigned short* Vp = VT + base;      // [d][s]

  __shared__ unsigned short Ks[2][4][64*32]; // 2 x 16 KB
  __shared__ unsigned short Vl[2][128*64];   // 2 x 16 KB
  __shared__ unsigned short Ps[64][72];      // 9 KB

  const int tid  = threadIdx.x;
  const int w    = tid >> 6, lane = tid & 63;
  const int quad = lane >> 4, lm = lane & 15;
  const int swz4 = (lm >> 1) & 3;
  const int swz8 = lm & 7;
  const int cgK = ((tid & 3) ^ ((tid >> 3) & 3)) * 8;
  const int cgV = ((tid & 7) ^ ((tid >> 3) & 7)) * 8;

  const float K1 = 0.1275156876f;            // (1/sqrt(128)) * log2(e)
  const f32x4 zero4 = {0.f, 0.f, 0.f, 0.f};
  const __bf16 one = (__bf16)1.0f;
  const bf16x8 vones = {one, one, one, one, one, one, one, one};

  auto stage = [&](int buf, int kt) {
    const unsigned short* krow = Kp + (size_t)(kt * 64 + (tid >> 2)) * HEAD_SIZE + cgK;
#pragma unroll
    for (int kk = 0; kk < 4; kk++)
      cp16((char*)&Ks[buf][kk][0] + tid * 16, krow + kk * 32);
#pragma unroll
    for (int i = 0; i < 4; i++) {
      int off = i * 4096 + tid * 16;
      int d = off >> 7;
      cp16((char*)&Vl[buf][0] + off, Vp + (size_t)d * SEQ + kt * 64 + cgV);
    }
  };

  int buf = 0;
  stage(0, 0);

  for (int ph = 0; ph < 2; ph++) {
    const int qt = ph ? qb : qa;
    bf16x8 qf[4];
    {
      const unsigned short* qrow = Qp + (size_t)(qt * 64 + w * 16 + lm) * HEAD_SIZE;
#pragma unroll
      for (int kk = 0; kk < 4; kk++)
        qf[kk] = *(const bf16x8*)(qrow + kk * 32 + quad * 8);
    }
    float m_r[4];
#pragma unroll
    for (int r = 0; r < 4; r++) m_r[r] = -1e30f;
    f32x4 lacc = zero4;
    f32x4 o[8];
#pragma unroll
    for (int i = 0; i < 8; i++) o[i] = zero4;

    for (int kt = 0; kt <= qt; ++kt) {
      __syncthreads();
      bool last = (ph == 1) && (kt == qt);
      if (!last) stage(buf ^ 1, (kt < qt) ? kt + 1 : 0);

      f32x4 sf[4];
#pragma unroll
      for (int nf = 0; nf < 4; nf++) {
        f32x4 accs = zero4;
#pragma unroll
        for (int kk = 0; kk < 4; kk++) {
          bf16x8 kfrag = *(const bf16x8*)(&Ks[buf][kk][(nf * 16 + lm) * 32 + (quad ^ swz4) * 8]);
          accs = __builtin_amdgcn_mfma_f32_16x16x32_bf16(qf[kk], kfrag, accs, 0, 0, 0);
        }
        sf[nf] = accs;
      }
      if (kt == qt) {
        int qrow0 = qt * 64 + w * 16 + quad * 4;
#pragma unroll
        for (int nf = 0; nf < 4; nf++) {
          int col = kt * 64 + nf * 16 + lm;
#pragma unroll
          for (int r = 0; r < 4; r++)
            if (col > qrow0 + r) sf[nf][r] = -1e30f;
        }
      }
      float alpha[4];
#pragma unroll
      for (int r = 0; r < 4; r++) {
        float v = fmaxf(fmaxf(sf[0][r], sf[1][r]), fmaxf(sf[2][r], sf[3][r]));
        v = fmaxf(v, __shfl_xor(v, 1));
        v = fmaxf(v, __shfl_xor(v, 2));
        v = fmaxf(v, __shfl_xor(v, 4));
        v = fmaxf(v, __shfl_xor(v, 8));
        float mn = fmaxf(m_r[r], v);
        alpha[r] = exp2f((m_r[r] - mn) * K1);
        m_r[r] = mn;
      }
#pragma unroll
      for (int nf = 0; nf < 4; nf++)
#pragma unroll
        for (int r = 0; r < 4; r++) {
          float p = exp2f((sf[nf][r] - m_r[r]) * K1);
          Ps[w * 16 + quad * 4 + r][nf * 16 + lm] = f2bf(p);
        }
#pragma unroll
      for (int df = 0; df < 8; df++)
#pragma unroll
        for (int r = 0; r < 4; r++) o[df][r] *= alpha[r];
#pragma unroll
      for (int r = 0; r < 4; r++) lacc[r] *= alpha[r];

#pragma unroll
      for (int ks = 0; ks < 2; ks++) {
        bf16x8 pf = *(const bf16x8*)(&Ps[w * 16 + lm][ks * 32 + quad * 8]);
        lacc = __builtin_amdgcn_mfma_f32_16x16x32_bf16(pf, vones, lacc, 0, 0, 0);
#pragma unroll
        for (int df = 0; df < 8; df++) {
          bf16x8 vf = *(const bf16x8*)(&Vl[buf][(df * 16 + lm) * 64 + (((ks * 4 + quad) ^ swz8)) * 8]);
          o[df] = __builtin_amdgcn_mfma_f32_16x16x32_bf16(pf, vf, o[df], 0, 0, 0);
        }
      }
      buf ^= 1;
    }

    float rl[4];
#pragma unroll
    for (int r = 0; r < 4; r++) rl[r] = 1.f / lacc[r];
    int row0 = b * SEQ + qt * 64 + w * 16 + quad * 4;
#pragma unroll
    for (int df = 0; df < 8; df++) {
      int col = h * HEAD_SIZE + df * 16 + lm;
#pragma unroll
      for (int r = 0; r < 4; r++)
        O[(size_t)(row0 + r) * HIDDEN + col] = f2bf(o[df][r] * rl[r]);
    }
  }
}

// ---------------------------------------------------------------- launch
extern "C" void kernel_launch(void* const* d_in, const int* in_sizes, int n_in,
                              void* d_out, int out_size, void* d_ws, size_t ws_size,
                              hipStream_t stream)
{
  const float* hs   = (const float*)d_in[0];
  const float* wqkv = (const float*)d_in[2];
  const float* bqkv = (const float*)d_in[3];
  const float* wd   = (const float*)d_in[4];
  const float* bd   = (const float*)d_in[5];
  const int*   pos  = (const int*)d_in[6];

  char* ws = (char*)d_ws;
  unsigned short* hsb = (unsigned short*)ws;  ws += (size_t)TOTAL * HIDDEN * 2;   // 16.8 MB
  unsigned short* wqb = (unsigned short*)ws;  ws += (size_t)QKV_N * HIDDEN * 2;   // 25.2 MB
  unsigned short* wdb = (unsigned short*)ws;  ws += (size_t)HIDDEN * HIDDEN * 2;  //  8.4 MB
  unsigned short* Qb  = (unsigned short*)ws;  ws += (size_t)TOTAL * HIDDEN * 2;
  unsigned short* Kb  = (unsigned short*)ws;  ws += (size_t)TOTAL * HIDDEN * 2;
  unsigned short* Vt  = (unsigned short*)ws;  ws += (size_t)TOTAL * HIDDEN * 2;   // [B,H,D,S]
  unsigned short* attnb = hsb;               // hsb dead after QKV GEMM
  if (ws_size < (size_t)(ws - (char*)d_ws)) return;  // ~100.8 MB needed

  const int na = TOTAL * HIDDEN, nb = QKV_N * HIDDEN, nc = HIDDEN * HIDDEN;
  f32_to_bf16_multi<<<(na + nb + nc) / 1024, 256, 0, stream>>>(
      hs, hsb, na, wqkv, wqb, nb, wd, wdb, nc);

  gemm_qkv<<<dim3(QKV_N / 256, TOTAL / 128), 256, 0, stream>>>(
      hsb, wqb, bqkv, pos, Qb, Kb, Vt, TOTAL, QKV_N, HIDDEN);

  flash_attn_k<<<dim3(64, 8), 256, 0, stream>>>(Qb, Kb, Vt, attnb);

  gemm_dense<<<dim3(HIDDEN / 128, TOTAL / 128), 256, 0, stream>>>(
      attnb, wdb, bd, (float*)d_out, TOTAL, HIDDEN, HIDDEN);
}